// Round 17
// baseline (843.463 us; speedup 1.0000x reference)
//
#include <hip/hip_runtime.h>
#include <hip/hip_bf16.h>
#include <math.h>

#define MC      16384
#define NSTEPS  120
#define PER     30
#define NMAT    4
#define NSTR    21
#define RRATE   0.05f
#define NBLK    2048
#define NSAMP   8
#define HSTEP   (1.0f/120.0f)
#define SQH     0.09128709291752769f   // sqrt(1/120)

typedef short short8  __attribute__((ext_vector_type(8)));
typedef short short4v __attribute__((ext_vector_type(4)));
typedef float f32x4   __attribute__((ext_vector_type(4)));

// ws layout (floats)
#define WS_PRPART 0                         // [84][2][2048]
#define WS_EPART  (NMAT*NSTR*2*NBLK)        // 344064, [2048]
#define WS_MEANE  (WS_EPART + NBLK)         // 346112
#define WS_FRAGS  346116                    // byte offset %16==0

// out layout (floats)
#define OUT_PV    0
#define OUT_PVV   84
#define OUT_PEXO  168
#define OUT_MEAN  16552
#define OUT_VAR   16553
#define OUT_ERR   16554

__device__ __forceinline__ float tgridf(int i)  { return (float)i * HSTEP; }
__device__ __forceinline__ float strikef(int s) { return (float)(0.8 + (double)s * 0.02); }
__device__ __forceinline__ float softplusf(float x){
  return fmaxf(x, 0.0f) + __logf(1.0f + __expf(-fabsf(x)));
}
__device__ __forceinline__ unsigned short f2bf(float f){
  __hip_bfloat16 b = __float2bfloat16(f);
  return __builtin_bit_cast(unsigned short, b);
}
__device__ __forceinline__ float bf2f(unsigned short u){
  return __builtin_bit_cast(float, ((unsigned)u)<<16);
}
__device__ __forceinline__ unsigned pk2(float a, float b){
  return (unsigned)f2bf(a) | ((unsigned)f2bf(b)<<16);
}
// swizzled byte addr in [16 rows x 128 cols] bf16 tile (256 B/row, 16 slots of 16B)
__device__ __forceinline__ int swaddr(int row, int slot, int inner){
  return row*256 + (((slot + row) & 15) << 4) + inner;
}
__device__ __forceinline__ short8 rdA(const unsigned short* H, int base, int lane){
  int addr = swaddr(lane&15, base + (lane>>4), 0);
  return *(const short8*)((const char*)H + addr);
}
__device__ __forceinline__ f32x4 mm(short8 a, short8 b, f32x4 c){
  return __builtin_amdgcn_mfma_f32_16x16x32_bf16(a, b, c, 0, 0, 0);
}
// D-store (relu); bias folded into MFMA via constant-1 K-row
__device__ __forceinline__ void stD(unsigned short* H, int colbase, int lane,
                                    f32x4 acc, bool relu){
  int col  = colbase + (lane & 15);
  int slot = col >> 3, inner = (col & 7)*2;
  #pragma unroll
  for (int i2=0;i2<4;++i2){
    int rw = ((lane>>4)<<2) + i2;
    float v = acc[i2];
    if (relu) v = fmaxf(v, 0.0f);
    *(unsigned short*)((char*)H + swaddr(rw, slot, inner)) = f2bf(v);
  }
}
// d-net B frag with bias row at k==50 and 1-propagator at (50,50)
__device__ __forceinline__ short8 mkBd(const float* __restrict__ W, const float* __restrict__ bias,
                                       int n0, int kt, int lane){
  short8 r;
  int n = n0 + (lane&15);
  #pragma unroll
  for (int i2=0;i2<8;++i2){
    int k = kt*32 + ((lane>>4)<<3) + i2;
    float w;
    if (k<50)       w = (n<50)? W[k*50+n] : 0.f;
    else if (k==50) w = (n<50)? bias[n] : ((n==50)? 1.f : 0.f);
    else            w = 0.f;
    r[i2] = (short)f2bf(w);
  }
  return r;
}
// v/e-net B frag (K tile 0..31) with bias row at k==KV, 1-propagator at (KV,KV)
__device__ __forceinline__ short8 mkBq(const float* __restrict__ W, const float* __restrict__ bias,
                                       int KV, int n0, int lane){
  short8 r;
  int n = n0 + (lane&15);
  #pragma unroll
  for (int i2=0;i2<8;++i2){
    int k = ((lane>>4)<<3) + i2;
    float w;
    if (k<KV)       w = (n<KV)? W[k*KV+n] : 0.f;
    else if (k==KV) w = (n<KV)? bias[n] : ((n==KV)? 1.f : 0.f);
    else            w = 0.f;
    r[i2] = (short)f2bf(w);
  }
  return r;
}

// ---- fragment prep: one block per (period, fid) -> ws[WS_FRAGS] ----
extern "C" __global__ void mk_frags(
    const float* __restrict__ dhW, const float* __restrict__ dhb,
    const float* __restrict__ vhW, const float* __restrict__ vhb,
    const float* __restrict__ ehW, const float* __restrict__ ehb,
    float* __restrict__ ws)
{
  const int bid = blockIdx.x;
  const int p   = bid / 36;
  const int fid = bid % 36;
  const int lane = threadIdx.x;
  short8 fr;
  if (fid < 24){
    int l = fid >> 3, nt = (fid >> 1) & 3, kt = fid & 1;
    fr = mkBd(dhW + p*7500 + l*2500, dhb + p*150 + l*50, nt*16, kt, lane);
  } else if (fid < 30){
    int q = fid - 24, l = q >> 1, nt = q & 1;
    fr = mkBq(vhW + p*2700 + l*900, vhb + p*90 + l*30, 30, nt*16, lane);
  } else {
    int q = fid - 30, l = q >> 1, nt = q & 1;
    fr = mkBq(ehW + p*1200 + l*400, ehb + p*60 + l*20, 20, nt*16, lane);
  }
  ((short8*)(ws + WS_FRAGS))[(p*36 + fid)*64 + lane] = fr;
}

extern "C" __global__ void __launch_bounds__(128,2) mc_main(
    const float* __restrict__ S0p, const float* __restrict__ z,
    const float* __restrict__ dW0, const float* __restrict__ db0,
    const float* __restrict__ dhW, const float* __restrict__ dhb,
    const float* __restrict__ dWo, const float* __restrict__ dbo,
    const float* __restrict__ vW0, const float* __restrict__ vb0,
    const float* __restrict__ vhW, const float* __restrict__ vhb,
    const float* __restrict__ vWo, const float* __restrict__ vbo,
    const float* __restrict__ eW0, const float* __restrict__ eb0,
    const float* __restrict__ ehW, const float* __restrict__ ehb,
    const float* __restrict__ eWo, const float* __restrict__ ebo,
    float* __restrict__ out, float* __restrict__ ws)
{
  __shared__ unsigned short Hb0[16*128];      // 4 KB (rows 8..15 stay zero)
  __shared__ unsigned short Hb1[16*128];      // 4 KB
  __shared__ float vh3f[16*40];               // 2.5 KB
  __shared__ float zper[NSAMP*30];            // 0.94 KB
  __shared__ unsigned short eW0perb[NMAT*600];// 4.7 KB (bf16)
  __shared__ float dW0s[128];
  __shared__ float db0s[64];
  __shared__ float vW0s[64];
  __shared__ float vb0s[32];
  __shared__ float eW0ts[20];
  __shared__ float eb0s[20];
  __shared__ float dWoL[64];
  __shared__ float eWoL[32];
  __shared__ float dtab[PER];
  __shared__ float Sb[NSAMP], ebuf[NSAMP];
  __shared__ float ydp[2][16];
  __shared__ float ype[16];
  __shared__ float part[84*2];

  const int tid  = threadIdx.x;
  const int lane = tid & 63;
  const int wid  = __builtin_amdgcn_readfirstlane(tid >> 6);  // 0..1
  const int blk  = blockIdx.x;
  const int r    = tid >> 4;          // sample row 0..7
  const int cc   = tid & 15;

  // zero whole tiles once (rows 8..15 must stay zero)
  for (int q=tid; q<16*128; q+=128){ Hb0[q]=0; Hb1[q]=0; }

  // wave roles: wave w handles d-ntiles {2w,2w+1}; wave0 = v, wave1 = e
  const bool isv = (wid == 0);
  const int  ntA = wid*2, ntB = wid*2+1;

  const float S0v = S0p[0];
  float S = S0v, runmax = S0v, cvE = 0.f;
  f32x4 rr[3];
  #pragma unroll
  for (int q=0;q<3;++q){ rr[q][0]=0.f; rr[q][1]=0.f; rr[q][2]=0.f; rr[q][3]=0.f; }
  float aE[NMAT][2];
  #pragma unroll
  for (int mt2=0;mt2<NMAT;++mt2){ aE[mt2][0]=0.f; aE[mt2][1]=0.f; }
  float G0=0.f, G1=0.f;

  #pragma unroll 1
  for (int p=0;p<NMAT;++p){
    // ---- per-period staging ----
    for (int q=tid; q<NSAMP*30; q+=128){ int r2=q/30, c2=q%30; zper[q] = z[(size_t)(blk*NSAMP+r2)*NSTEPS + p*30 + c2]; }
    for (int q=tid; q<NMAT*600; q+=128){ int mat=q/600, k=q%600; eW0perb[q] = f2bf(eW0[mat*2440 + p*600 + 20 + k]); }
    { int rw = tid>>6, j = tid&63; dW0s[tid] = (j<50)? dW0[p*100 + rw*50 + j] : 0.f; }
    if (tid < 64) db0s[tid] = (tid<50)? db0[p*50+tid] : ((tid==50)? 1.f : 0.f);
    else { int idx = tid-64, rw = idx>>5, j = idx&31; vW0s[idx] = (j<30)? vW0[p*60 + rw*30 + j] : 0.f; }
    if (tid < 32)       vb0s[tid] = (tid<30)? vb0[p*30+tid] : ((tid==30)? 1.f : 0.f);
    else if (tid < 52){ int j=tid-32; eW0ts[j]=eW0[p*2440+j]; eb0s[j]=eb0[p*20+j]; }
    else if (tid >= 64){ int j=tid-64; dWoL[j] = (j<50)? dWo[p*50+j] : 0.f; }
    if (tid < 32)       eWoL[tid] = (tid<20)? eWo[p*20+tid] : 0.f;
    else if (tid < 62){ int j=tid-32; dtab[j] = __expf(-RRATE * ((float)(p*PER+j) * HSTEP)); }

    const float dboS = dbo[p], eboS = ebo[p];
    const int fq0 = isv ? 24 : 30;

    __syncthreads();   // staging visible to ALL waves before any LDS read

    // head weights per lane (AFTER barrier — cross-wave staged data)
    const float wdA = dWoL[ntA*16 + (lane&15)];
    const float wdB = dWoL[ntB*16 + (lane&15)];
    const float weA = eWoL[lane&15];
    const float weB = eWoL[16 + (lane&15)];

    #pragma unroll 1
    for (int ii=1; ii<=PER; ++ii){
      const float t0  = tgridf(p*PER + ii - 1);

      // blur the frag base each step so loads can't be LICM-hoisted
      const short8* FBp;
      { uintptr_t u = (uintptr_t)(ws + WS_FRAGS); asm volatile("" : "+s"(u));
        FBp = (const short8*)u + (size_t)p*36*64 + lane; }

      // ---- pipeline: issue phase-B frag loads BEFORE phase A ----
      short8 xA0 = FBp[(ntA*2+0)*64], xA1 = FBp[(ntA*2+1)*64];
      short8 xB0 = FBp[(ntB*2+0)*64], xB1 = FBp[(ntB*2+1)*64];
      short8 xQ0 = FBp[(fq0+0)*64],   xQ1 = FBp[(fq0+1)*64];

      // ======== phase A: all three H0 -> Hb0 (rows 0..7) ========
      {
        short4v hv;
        #pragma unroll
        for (int k=0;k<4;++k){
          int j = cc*4 + k;
          float u = fmaxf(fmaf(t0, dW0s[j], fmaf(S, dW0s[64+j], db0s[j])), 0.f);
          hv[k] = (short)f2bf(u);
        }
        *(short4v*)((char*)Hb0 + swaddr(r, cc>>1, (cc&1)*8)) = hv;
        {
          int j = cc*2;
          float u0 = fmaxf(fmaf(t0, vW0s[j],   fmaf(S, vW0s[32+j],   vb0s[j])),   0.f);
          float u1 = fmaxf(fmaf(t0, vW0s[j+1], fmaf(S, vW0s[32+j+1], vb0s[j+1])), 0.f);
          *(unsigned*)((char*)Hb0 + swaddr(r, 8+(cc>>2), (cc&3)*4)) = pk2(u0,u1);
        }
        unsigned ev = 0;
        if (cc < 10){
          const int o = (ii-1)*20 + cc*2;
          unsigned p0 = *(const unsigned*)&eW0perb[        o];
          unsigned p1 = *(const unsigned*)&eW0perb[ 600 +  o];
          unsigned p2 = *(const unsigned*)&eW0perb[1200 +  o];
          unsigned p3 = *(const unsigned*)&eW0perb[1800 +  o];
          aE[0][0] = fmaf(S, bf2f((unsigned short)(p0&0xffff)), aE[0][0]);
          aE[0][1] = fmaf(S, bf2f((unsigned short)(p0>>16)),    aE[0][1]);
          aE[1][0] = fmaf(S, bf2f((unsigned short)(p1&0xffff)), aE[1][0]);
          aE[1][1] = fmaf(S, bf2f((unsigned short)(p1>>16)),    aE[1][1]);
          aE[2][0] = fmaf(S, bf2f((unsigned short)(p2&0xffff)), aE[2][0]);
          aE[2][1] = fmaf(S, bf2f((unsigned short)(p2>>16)),    aE[2][1]);
          aE[3][0] = fmaf(S, bf2f((unsigned short)(p3&0xffff)), aE[3][0]);
          aE[3][1] = fmaf(S, bf2f((unsigned short)(p3>>16)),    aE[3][1]);
          float a0 = (p==0)?aE[0][0]:(p==1)?aE[1][0]:(p==2)?aE[2][0]:aE[3][0];
          float a1 = (p==0)?aE[0][1]:(p==1)?aE[1][1]:(p==2)?aE[2][1]:aE[3][1];
          int j = cc*2;
          float e0 = fmaxf(t0*eW0ts[j]   + a0 + eb0s[j],   0.f);
          float e1 = fmaxf(t0*eW0ts[j+1] + a1 + eb0s[j+1], 0.f);
          ev = pk2(e0,e1);
        } else if (cc == 10){
          ev = 0x3F80u;   // bf16 1.0 at e-col 20 (bias propagator), col 21 = 0
        }
        *(unsigned*)((char*)Hb0 + swaddr(r, 12+(cc>>2), (cc&3)*4)) = ev;
      }
      __syncthreads();
      // ======== phase B: L1  Hb0 -> Hb1 (uses x*, prefetches y*) ========
      short8 yA0 = FBp[(8+ntA*2+0)*64], yA1 = FBp[(8+ntA*2+1)*64];
      short8 yB0 = FBp[(8+ntB*2+0)*64], yB1 = FBp[(8+ntB*2+1)*64];
      short8 yQ0 = FBp[(fq0+2+0)*64],   yQ1 = FBp[(fq0+2+1)*64];
      {
        short8 a0 = rdA(Hb0,0,lane), a1 = rdA(Hb0,4,lane);
        short8 aq = rdA(Hb0, isv?8:12, lane);
        f32x4 c0={0.f,0.f,0.f,0.f}, c1={0.f,0.f,0.f,0.f};
        c0=mm(a0,xA0,c0); c0=mm(a1,xA1,c0);
        c1=mm(a0,xB0,c1); c1=mm(a1,xB1,c1);
        stD(Hb1, ntA*16, lane, c0, true);
        stD(Hb1, ntB*16, lane, c1, true);
        f32x4 cq0={0.f,0.f,0.f,0.f}, cq1={0.f,0.f,0.f,0.f};
        cq0=mm(aq,xQ0,cq0); cq1=mm(aq,xQ1,cq1);
        stD(Hb1, (isv?64:96)+0,  lane, cq0, true);
        stD(Hb1, (isv?64:96)+16, lane, cq1, true);
      }
      __syncthreads();
      // ======== phase C: L2  Hb1 -> Hb0 (uses y*, prefetches z*) ========
      short8 zA0 = FBp[(16+ntA*2+0)*64], zA1 = FBp[(16+ntA*2+1)*64];
      short8 zB0 = FBp[(16+ntB*2+0)*64], zB1 = FBp[(16+ntB*2+1)*64];
      short8 zQ0 = FBp[(fq0+4+0)*64],    zQ1 = FBp[(fq0+4+1)*64];
      {
        short8 a0 = rdA(Hb1,0,lane), a1 = rdA(Hb1,4,lane);
        short8 aq = rdA(Hb1, isv?8:12, lane);
        f32x4 c0={0.f,0.f,0.f,0.f}, c1={0.f,0.f,0.f,0.f};
        c0=mm(a0,yA0,c0); c0=mm(a1,yA1,c0);
        c1=mm(a0,yB0,c1); c1=mm(a1,yB1,c1);
        stD(Hb0, ntA*16, lane, c0, true);
        stD(Hb0, ntB*16, lane, c1, true);
        f32x4 cq0={0.f,0.f,0.f,0.f}, cq1={0.f,0.f,0.f,0.f};
        cq0=mm(aq,yQ0,cq0); cq1=mm(aq,yQ1,cq1);
        stD(Hb0, (isv?64:96)+0,  lane, cq0, true);
        stD(Hb0, (isv?64:96)+16, lane, cq1, true);
      }
      __syncthreads();
      // ======== phase D: L3 (d,e heads in-register; v -> vh3f) ========
      {
        short8 a0 = rdA(Hb0,0,lane), a1 = rdA(Hb0,4,lane);
        short8 aq = rdA(Hb0, isv?8:12, lane);
        f32x4 c0={0.f,0.f,0.f,0.f}, c1={0.f,0.f,0.f,0.f};
        c0=mm(a0,zA0,c0); c0=mm(a1,zA1,c0);
        c1=mm(a0,zB0,c1); c1=mm(a1,zB1,c1);
        f32x4 pd;
        #pragma unroll
        for (int i2=0;i2<4;++i2)
          pd[i2] = fmaf(fmaxf(c0[i2],0.f), wdA, fmaxf(c1[i2],0.f)*wdB);
        f32x4 cq0={0.f,0.f,0.f,0.f}, cq1={0.f,0.f,0.f,0.f};
        cq0=mm(aq,zQ0,cq0); cq1=mm(aq,zQ1,cq1);
        #pragma unroll
        for (int mk=1; mk<16; mk<<=1){
          #pragma unroll
          for (int i2=0;i2<4;++i2) pd[i2] += __shfl_xor(pd[i2], mk);
        }
        if ((lane&15)==0){
          int rg = (lane>>4)<<2;
          #pragma unroll
          for (int i2=0;i2<4;++i2) ydp[wid][rg+i2] = pd[i2];
        }
        if (isv){
          #pragma unroll
          for (int i2=0;i2<4;++i2){
            int r0 = ((lane>>4)<<2) + i2;
            vh3f[r0*40 +      (lane&15)] = fmaxf(cq0[i2], 0.f);
            vh3f[r0*40 + 16 + (lane&15)] = fmaxf(cq1[i2], 0.f);
          }
        } else {
          f32x4 pe;
          #pragma unroll
          for (int i2=0;i2<4;++i2)
            pe[i2] = fmaf(fmaxf(cq0[i2],0.f), weA, fmaxf(cq1[i2],0.f)*weB);
          #pragma unroll
          for (int mk=1; mk<16; mk<<=1){
            #pragma unroll
            for (int i2=0;i2<4;++i2) pe[i2] += __shfl_xor(pe[i2], mk);
          }
          if ((lane&15)==0){
            int rg = (lane>>4)<<2;
            #pragma unroll
            for (int i2=0;i2<4;++i2) ype[rg+i2] = pe[i2];
          }
        }
      }
      __syncthreads();
      // ======== phase F: heads (LDS broadcast) + scalars + G-accum ========
      {
        const float y    = ydp[0][r] + ydp[1][r] + dboS;
        const float yep  = ype[r];
        const float diff = softplusf(y);
        const float zv   = zper[r*30 + (ii-1)];
        const float dWn  = SQH * zv;
        const float d1 = 1.f + (RRATE*SQH)*S;
        const float d2 = 1.f + S*diff*SQH;
        const float Snew = S + (RRATE*HSTEP)*S*__builtin_amdgcn_rcpf(d1)
                             + S*diff*dWn*__builtin_amdgcn_rcpf(d2);
        const float disc = dtab[ii-1];
        const float coef = disc * S * diff * dWn;
        cvE = fmaf(coef, yep + eboS, cvE);
        runmax = fmaxf(runmax, Snew);
        {
          float2 vv = *(const float2*)&vh3f[r*40 + cc*2];  // col 30 == 1.0 -> G[30] = C
          G0 = fmaf(coef, vv.x, G0);
          G1 = fmaf(coef, vv.y, G1);
        }
        S = Snew;

        if (ii==PER){
          *(unsigned*)((char*)Hb0 + swaddr(r, cc>>2, (cc&3)*4)) = pk2(G0,G1);
          G0=0.f; G1=0.f;
          if (cc==0) Sb[r] = S;
        }
      }

      if (ii==PER){
        __syncthreads();
        // ======== M2: RR += [G|C] @ [vWo;vbo] ; pr stats (6 col-tiles / 2 waves) ========
        const float disc_i = __expf(-RRATE * ((float)(p+1) * 0.25f));
        const float* vWop = vWo + p*2520;
        const float* vbop = vbo + p*84;
        #pragma unroll
        for (int q3=0;q3<3;++q3){
          const int ntr = wid*3 + q3;         // 0..5
          short8 a = rdA(Hb0, 0, lane);
          const int col = ntr*16 + (lane&15);
          short8 bw;
          #pragma unroll
          for (int i2=0;i2<8;++i2){
            int k = ((lane>>4)<<3)+i2;
            float w = 0.f;
            if (col < 84){
              if (k < 30)       w = vWop[k*84+col];
              else if (k == 30) w = vbop[col];
            }
            bw[i2] = (short)f2bf(w);
          }
          f32x4 d4 = {0.f,0.f,0.f,0.f};
          d4 = mm(a,bw,d4);
          const int s = col - p*NSTR;
          const bool inr = (s>=0) && (s<NSTR) && (col<84);
          const float K = strikef(s);
          float ssum=0.f, ssq=0.f;
          #pragma unroll
          for (int i2=0;i2<4;++i2){
            int row = ((lane>>4)<<2) + i2;
            rr[q3][i2] += d4[i2];
            if (row < NSAMP && inr){
              float pr = disc_i*fmaxf(Sb[row]-K,0.f) - rr[q3][i2];
              ssum += pr; ssq = fmaf(pr,pr,ssq);
            }
          }
          ssum += __shfl_down(ssum,16); ssum += __shfl_down(ssum,32);
          ssq  += __shfl_down(ssq ,16); ssq  += __shfl_down(ssq ,32);
          if (inr && lane<16){
            part[col*2+0] = ssum;
            part[col*2+1] = ssq;
          }
        }
        __syncthreads();
        // ======== M3: write per-block partials ========
        if (tid < NSTR){
          int cidx = p*NSTR + tid;
          ws[WS_PRPART + (cidx*2+0)*NBLK + blk] = part[cidx*2];
        } else if (tid >= 64 && tid < 64+NSTR){
          int cidx = p*NSTR + (tid-64);
          ws[WS_PRPART + (cidx*2+1)*NBLK + blk] = part[cidx*2+1];
        }
        __syncthreads();   // protect LDS from next period's staging writes
      }
    }
  }

  // ---- epilogue ----
  if (cc==0){
    const float discT = __expf(-RRATE);
    const float e = discT * (runmax - S);
    out[OUT_PEXO + blk*NSAMP + r] = e - cvE;
    ebuf[r] = e;
  }
  __syncthreads();
  if (tid < NSAMP){
    float se = ebuf[tid];
    se += __shfl_down(se,4); se += __shfl_down(se,2); se += __shfl_down(se,1);
    if (tid==0) ws[WS_EPART + blk] = se;
  }
}

extern "C" __global__ void fin_pv(const float* __restrict__ ws, float* __restrict__ out){
  const int t    = blockIdx.x;       // 0..83
  const int lane = threadIdx.x;      // 0..63
  float sum=0.0f, ssq=0.0f;
  for (int b=lane; b<NBLK; b+=64){
    sum += ws[WS_PRPART + (t*2+0)*NBLK + b];
    ssq += ws[WS_PRPART + (t*2+1)*NBLK + b];
  }
  for (int o=32;o>0;o>>=1){ sum += __shfl_down(sum,o); ssq += __shfl_down(ssq,o); }
  if (lane==0){
    out[OUT_PV  + t] = sum * (1.0f/MC);
    out[OUT_PVV + t] = (ssq - sum*sum*(1.0f/MC)) * (1.0f/(MC-1));
  }
}

extern "C" __global__ void fin_pe(float* out, float* ws){
  __shared__ float sA[4], sB[4], sC[4];
  const int t = threadIdx.x;
  float sum=0.0f, ssq=0.0f;
  for (int idx=t; idx<MC; idx+=256){
    const float v = out[OUT_PEXO+idx];
    sum += v; ssq = fmaf(v,v,ssq);
  }
  float es = 0.0f;
  for (int idx=t; idx<NBLK; idx+=256) es += ws[WS_EPART + idx];
  for (int o=32;o>0;o>>=1){
    sum += __shfl_down(sum,o);
    ssq += __shfl_down(ssq,o);
    es  += __shfl_down(es,o);
  }
  const int w=t>>6, lane=t&63;
  if (lane==0){ sA[w]=sum; sB[w]=ssq; sC[w]=es; }
  __syncthreads();
  if (t==0){
    const float s=sA[0]+sA[1]+sA[2]+sA[3];
    const float q=sB[0]+sB[1]+sB[2]+sB[3];
    const float e=sC[0]+sC[1]+sC[2]+sC[3];
    out[OUT_MEAN]=s*(1.0f/MC);
    out[OUT_VAR]=(q - s*s*(1.0f/MC))*(1.0f/(MC-1));
    ws[WS_MEANE]=e*(1.0f/MC);
  }
}

extern "C" __global__ void fin_err(float* out, const float* __restrict__ ws){
  const int m = blockIdx.x*blockDim.x + threadIdx.x;
  if (m < MC) out[OUT_ERR+m] = out[OUT_PEXO+m] - ws[WS_MEANE];
}

extern "C" void kernel_launch(void* const* d_in, const int* in_sizes, int n_in,
                              void* d_out, int out_size, void* d_ws, size_t ws_size,
                              hipStream_t stream){
  (void)in_sizes; (void)n_in; (void)out_size; (void)ws_size;
  const float* S0 =(const float*)d_in[0];
  const float* z  =(const float*)d_in[1];
  const float* dW0=(const float*)d_in[2];
  const float* db0=(const float*)d_in[3];
  const float* dhW=(const float*)d_in[4];
  const float* dhb=(const float*)d_in[5];
  const float* dWo=(const float*)d_in[6];
  const float* dbo=(const float*)d_in[7];
  const float* vW0=(const float*)d_in[8];
  const float* vb0=(const float*)d_in[9];
  const float* vhW=(const float*)d_in[10];
  const float* vhb=(const float*)d_in[11];
  const float* vWo=(const float*)d_in[12];
  const float* vbo=(const float*)d_in[13];
  const float* eW0=(const float*)d_in[14];
  const float* eb0=(const float*)d_in[15];
  const float* ehW=(const float*)d_in[16];
  const float* ehb=(const float*)d_in[17];
  const float* eWo=(const float*)d_in[18];
  const float* ebo=(const float*)d_in[19];
  float* out=(float*)d_out;
  float* ws =(float*)d_ws;

  mk_frags<<<dim3(NMAT*36),dim3(64),0,stream>>>(dhW,dhb,vhW,vhb,ehW,ehb,ws);
  mc_main<<<dim3(NBLK),dim3(128),0,stream>>>(S0,z,dW0,db0,dhW,dhb,dWo,dbo,
                                             vW0,vb0,vhW,vhb,vWo,vbo,
                                             eW0,eb0,ehW,ehb,eWo,ebo,out,ws);
  fin_pv <<<dim3(84), dim3(64),0,stream>>>(ws,out);
  fin_pe <<<dim3(1), dim3(256),0,stream>>>(out,ws);
  fin_err<<<dim3(64),dim3(256),0,stream>>>(out,ws);
}

// Round 18
// 417.412 us; speedup vs baseline: 2.0207x; 2.0207x over previous
//
#include <hip/hip_runtime.h>
#include <hip/hip_bf16.h>
#include <math.h>

#define MC      16384
#define NSTEPS  120
#define PER     30
#define NMAT    4
#define NSTR    21
#define RRATE   0.05f
#define NBLK    1024
#define NSAMP   16
#define HSTEP   (1.0f/120.0f)
#define SQH     0.09128709291752769f   // sqrt(1/120)

typedef short short8  __attribute__((ext_vector_type(8)));
typedef short short4v __attribute__((ext_vector_type(4)));
typedef float f32x4   __attribute__((ext_vector_type(4)));

// ws layout (floats)
#define WS_PRPART 0                         // [84][2][1024]
#define WS_EPART  (NMAT*NSTR*2*NBLK)        // [1024] = 172032
#define WS_MEANE  (WS_EPART + NBLK)         // 173056
#define WS_FRAGS  173060                    // 16B-aligned (173060*4 % 16 == 0)

// out layout (floats)
#define OUT_PV    0
#define OUT_PVV   84
#define OUT_PEXO  168
#define OUT_MEAN  16552
#define OUT_VAR   16553
#define OUT_ERR   16554

__device__ __forceinline__ float tgridf(int i)  { return (float)i * HSTEP; }
__device__ __forceinline__ float strikef(int s) { return (float)(0.8 + (double)s * 0.02); }
__device__ __forceinline__ float softplusf(float x){
  return fmaxf(x, 0.0f) + __logf(1.0f + __expf(-fabsf(x)));
}
__device__ __forceinline__ unsigned short f2bf(float f){
  __hip_bfloat16 b = __float2bfloat16(f);
  return __builtin_bit_cast(unsigned short, b);
}
__device__ __forceinline__ float bf2f(unsigned short u){
  return __builtin_bit_cast(float, ((unsigned)u)<<16);
}
// swizzled byte addr in [16 rows x 128 cols] bf16 tile (256 B/row, 16 slots of 16B)
__device__ __forceinline__ int swaddr(int row, int slot, int inner){
  return row*256 + (((slot + row) & 15) << 4) + inner;
}
__device__ __forceinline__ short8 rdA(const unsigned short* H, int base, int lane){
  int addr = swaddr(lane&15, base + (lane>>4), 0);
  return *(const short8*)((const char*)H + addr);
}
__device__ __forceinline__ f32x4 mm(short8 a, short8 b, f32x4 c){
  return __builtin_amdgcn_mfma_f32_16x16x32_bf16(a, b, c, 0, 0, 0);
}
// D-store (relu); bias folded into MFMA via constant-1 K-row
__device__ __forceinline__ void stD(unsigned short* H, int colbase, int lane,
                                    f32x4 acc, bool relu){
  int col  = colbase + (lane & 15);
  int slot = col >> 3, inner = (col & 7)*2;
  #pragma unroll
  for (int i2=0;i2<4;++i2){
    int rw = ((lane>>4)<<2) + i2;
    float v = acc[i2];
    if (relu) v = fmaxf(v, 0.0f);
    *(unsigned short*)((char*)H + swaddr(rw, slot, inner)) = f2bf(v);
  }
}
// d-net B frag with bias row at k==50 and 1-propagator at (50,50)
__device__ __forceinline__ short8 mkBd(const float* __restrict__ W, const float* __restrict__ bias,
                                       int n0, int kt, int lane){
  short8 r;
  int n = n0 + (lane&15);
  #pragma unroll
  for (int i2=0;i2<8;++i2){
    int k = kt*32 + ((lane>>4)<<3) + i2;
    float w;
    if (k<50)       w = (n<50)? W[k*50+n] : 0.f;
    else if (k==50) w = (n<50)? bias[n] : ((n==50)? 1.f : 0.f);
    else            w = 0.f;
    r[i2] = (short)f2bf(w);
  }
  return r;
}
// v/e-net B frag (K tile 0..31) with bias row at k==KV, 1-propagator at (KV,KV)
__device__ __forceinline__ short8 mkBq(const float* __restrict__ W, const float* __restrict__ bias,
                                       int KV, int n0, int lane){
  short8 r;
  int n = n0 + (lane&15);
  #pragma unroll
  for (int i2=0;i2<8;++i2){
    int k = ((lane>>4)<<3) + i2;
    float w;
    if (k<KV)       w = (n<KV)? W[k*KV+n] : 0.f;
    else if (k==KV) w = (n<KV)? bias[n] : ((n==KV)? 1.f : 0.f);
    else            w = 0.f;
    r[i2] = (short)f2bf(w);
  }
  return r;
}

// ---- fragment prep: one block per (period, fid) -> ws[WS_FRAGS] ----
extern "C" __global__ void mk_frags(
    const float* __restrict__ dhW, const float* __restrict__ dhb,
    const float* __restrict__ vhW, const float* __restrict__ vhb,
    const float* __restrict__ ehW, const float* __restrict__ ehb,
    float* __restrict__ ws)
{
  const int bid = blockIdx.x;
  const int p   = bid / 36;
  const int fid = bid % 36;
  const int lane = threadIdx.x;
  short8 fr;
  if (fid < 24){
    int l = fid >> 3, nt = (fid >> 1) & 3, kt = fid & 1;
    fr = mkBd(dhW + p*7500 + l*2500, dhb + p*150 + l*50, nt*16, kt, lane);
  } else if (fid < 30){
    int q = fid - 24, l = q >> 1, nt = q & 1;
    fr = mkBq(vhW + p*2700 + l*900, vhb + p*90 + l*30, 30, nt*16, lane);
  } else {
    int q = fid - 30, l = q >> 1, nt = q & 1;
    fr = mkBq(ehW + p*1200 + l*400, ehb + p*60 + l*20, 20, nt*16, lane);
  }
  ((short8*)(ws + WS_FRAGS))[(p*36 + fid)*64 + lane] = fr;
}

extern "C" __global__ void __launch_bounds__(128,2) mc_main(
    const float* __restrict__ S0p, const float* __restrict__ z,
    const float* __restrict__ dW0, const float* __restrict__ db0,
    const float* __restrict__ dhW, const float* __restrict__ dhb,
    const float* __restrict__ dWo, const float* __restrict__ dbo,
    const float* __restrict__ vW0, const float* __restrict__ vb0,
    const float* __restrict__ vhW, const float* __restrict__ vhb,
    const float* __restrict__ vWo, const float* __restrict__ vbo,
    const float* __restrict__ eW0, const float* __restrict__ eb0,
    const float* __restrict__ ehW, const float* __restrict__ ehb,
    const float* __restrict__ eWo, const float* __restrict__ ebo,
    float* __restrict__ out, float* __restrict__ ws)
{
  __shared__ unsigned short Hb0[NSAMP*128];   // 4 KB
  __shared__ unsigned short Hb1[NSAMP*128];   // 4 KB
  __shared__ float vh3f[NSAMP*40];            // 2.5 KB
  __shared__ float zper[NSAMP*30];            // 1.875 KB
  __shared__ float eW0per[NMAT*600];          // 9.375 KB
  __shared__ float dW0s[128];
  __shared__ float db0s[64];
  __shared__ float vW0s[64];
  __shared__ float vb0s[32];
  __shared__ float eW0ts[20];
  __shared__ float eb0s[20];
  __shared__ float dWoL[64];
  __shared__ float eWoL[32];
  __shared__ float dtab[PER];
  __shared__ float Sb[NSAMP], ebuf[NSAMP];
  __shared__ float ydp[2][NSAMP];             // per-wave d-head partials
  __shared__ float ype[NSAMP];                // e-head (wave 1 only)
  __shared__ float part[84*2];

  const int tid  = threadIdx.x;
  const int lane = tid & 63;
  const int wid  = __builtin_amdgcn_readfirstlane(tid >> 6);  // 0..1
  const int blk  = blockIdx.x;
  const int r    = tid >> 3;          // sample row 0..15
  const int cc   = tid & 7;

  // wave roles: wave w handles d-ntiles {2w,2w+1}; wave0 = v, wave1 = e
  const bool isv = (wid == 0);
  const int  ntA = wid*2, ntB = wid*2+1;

  const float S0v = S0p[0];
  float S = S0v, runmax = S0v, cvE = 0.f;
  f32x4 rr[3];
  #pragma unroll
  for (int q=0;q<3;++q){ rr[q][0]=0.f; rr[q][1]=0.f; rr[q][2]=0.f; rr[q][3]=0.f; }
  float aE[NMAT][4];
  #pragma unroll
  for (int mt2=0;mt2<NMAT;++mt2){ aE[mt2][0]=0.f; aE[mt2][1]=0.f; aE[mt2][2]=0.f; aE[mt2][3]=0.f; }
  float G_[4] = {0.f,0.f,0.f,0.f};

  #pragma unroll 1
  for (int p=0;p<NMAT;++p){
    // ---- per-period staging ----
    for (int q=tid; q<NSAMP*30; q+=128){ int r2=q/30, c2=q%30; zper[q] = z[(size_t)(blk*NSAMP+r2)*NSTEPS + p*30 + c2]; }
    for (int q=tid; q<NMAT*600; q+=128){ int mat=q/600, k=q%600; eW0per[q] = eW0[mat*2440 + p*600 + 20 + k]; }
    { int rw = tid>>6, j = tid&63; dW0s[tid] = (j<50)? dW0[p*100 + rw*50 + j] : 0.f; }
    if (tid < 64) db0s[tid] = (tid<50)? db0[p*50+tid] : ((tid==50)? 1.f : 0.f);
    else { int idx = tid-64, rw = idx>>5, j = idx&31; vW0s[idx] = (j<30)? vW0[p*60 + rw*30 + j] : 0.f; }
    if (tid < 32)       vb0s[tid] = (tid<30)? vb0[p*30+tid] : ((tid==30)? 1.f : 0.f);
    else if (tid < 64){ int j=tid-32; if (j<20){ eW0ts[j]=eW0[p*2440+j]; eb0s[j]=eb0[p*20+j]; } }
    else { int j=tid-64; dWoL[j] = (j<50)? dWo[p*50+j] : 0.f; }
    if (tid < 32)       eWoL[tid] = (tid<20)? eWo[p*20+tid] : 0.f;
    else if (tid < 62){ int j=tid-32; dtab[j] = __expf(-RRATE * ((float)(p*PER+j) * HSTEP)); }

    const float dboS = dbo[p], eboS = ebo[p];
    const int fq0 = isv ? 24 : 30;   // layer-0 q-frag fid base

    __syncthreads();   // staging visible to ALL waves before any LDS read

    // head weights per lane (AFTER barrier — cross-wave staged data)
    const float wdA = dWoL[ntA*16 + (lane&15)];
    const float wdB = dWoL[ntB*16 + (lane&15)];
    const float weA = eWoL[lane&15];
    const float weB = eWoL[16 + (lane&15)];

    #pragma unroll 1
    for (int ii=1; ii<=PER; ++ii){
      const float t0  = tgridf(p*PER + ii - 1);

      // blur the frag base each step so loads can't be LICM-hoisted across the p-loop
      const short8* FBp;
      { uintptr_t u = (uintptr_t)(ws + WS_FRAGS); asm volatile("" : "+s"(u));
        FBp = (const short8*)u + (size_t)p*36*64 + lane; }

      // ---- pipeline: issue phase-B frag loads BEFORE phase A ----
      short8 xA0 = FBp[(ntA*2+0)*64], xA1 = FBp[(ntA*2+1)*64];
      short8 xB0 = FBp[(ntB*2+0)*64], xB1 = FBp[(ntB*2+1)*64];
      short8 xQ0 = FBp[(fq0+0)*64],   xQ1 = FBp[(fq0+1)*64];

      // ======== phase A: all three H0 -> Hb0 ========
      {
        short8 hv;
        #pragma unroll
        for (int k=0;k<8;++k){
          int j = cc*8 + k;
          float u = fmaxf(fmaf(t0, dW0s[j], fmaf(S, dW0s[64+j], db0s[j])), 0.f);
          hv[k] = (short)f2bf(u);
        }
        *(short8*)((char*)Hb0 + swaddr(r, cc, 0)) = hv;
        short4v vv;
        #pragma unroll
        for (int k=0;k<4;++k){
          int j = cc*4 + k;
          float u = fmaxf(fmaf(t0, vW0s[j], fmaf(S, vW0s[32+j], vb0s[j])), 0.f);
          vv[k] = (short)f2bf(u);
        }
        *(short4v*)((char*)Hb0 + swaddr(r, 8+(cc>>1), (cc&1)*8)) = vv;
        short4v ev = {0,0,0,0};
        if (cc < 5){
          const int o = (ii-1)*20 + cc*4;
          f32x4 w0 = *(const f32x4*)&eW0per[        o];
          f32x4 w1 = *(const f32x4*)&eW0per[ 600 +  o];
          f32x4 w2 = *(const f32x4*)&eW0per[1200 +  o];
          f32x4 w3 = *(const f32x4*)&eW0per[1800 +  o];
          #pragma unroll
          for (int k=0;k<4;++k){
            aE[0][k] = fmaf(S, w0[k], aE[0][k]);
            aE[1][k] = fmaf(S, w1[k], aE[1][k]);
            aE[2][k] = fmaf(S, w2[k], aE[2][k]);
            aE[3][k] = fmaf(S, w3[k], aE[3][k]);
            float a = (p==0)?aE[0][k]:(p==1)?aE[1][k]:(p==2)?aE[2][k]:aE[3][k];
            int j = cc*4 + k;
            float e0 = fmaxf(t0*eW0ts[j] + a + eb0s[j], 0.f);
            ev[k] = (short)f2bf(e0);
          }
        } else if (cc == 5){
          ev[0] = (short)0x3F80;   // bf16 1.0 at e-col 20 (bias propagator)
        }
        *(short4v*)((char*)Hb0 + swaddr(r, 12+(cc>>1), (cc&1)*8)) = ev;
      }
      __syncthreads();
      // ======== phase B: L1  Hb0 -> Hb1 (uses x*, prefetches y* for C) ========
      short8 yA0 = FBp[(8+ntA*2+0)*64], yA1 = FBp[(8+ntA*2+1)*64];
      short8 yB0 = FBp[(8+ntB*2+0)*64], yB1 = FBp[(8+ntB*2+1)*64];
      short8 yQ0 = FBp[(fq0+2+0)*64],   yQ1 = FBp[(fq0+2+1)*64];
      {
        short8 a0 = rdA(Hb0,0,lane), a1 = rdA(Hb0,4,lane);
        short8 aq = rdA(Hb0, isv?8:12, lane);
        f32x4 c0={0.f,0.f,0.f,0.f}, c1={0.f,0.f,0.f,0.f};
        c0=mm(a0,xA0,c0); c0=mm(a1,xA1,c0);
        c1=mm(a0,xB0,c1); c1=mm(a1,xB1,c1);
        stD(Hb1, ntA*16, lane, c0, true);
        stD(Hb1, ntB*16, lane, c1, true);
        f32x4 cq0={0.f,0.f,0.f,0.f}, cq1={0.f,0.f,0.f,0.f};
        cq0=mm(aq,xQ0,cq0); cq1=mm(aq,xQ1,cq1);
        stD(Hb1, (isv?64:96)+0,  lane, cq0, true);
        stD(Hb1, (isv?64:96)+16, lane, cq1, true);
      }
      __syncthreads();
      // ======== phase C: L2  Hb1 -> Hb0 (uses y*, prefetches z* for D) ========
      short8 zA0 = FBp[(16+ntA*2+0)*64], zA1 = FBp[(16+ntA*2+1)*64];
      short8 zB0 = FBp[(16+ntB*2+0)*64], zB1 = FBp[(16+ntB*2+1)*64];
      short8 zQ0 = FBp[(fq0+4+0)*64],    zQ1 = FBp[(fq0+4+1)*64];
      {
        short8 a0 = rdA(Hb1,0,lane), a1 = rdA(Hb1,4,lane);
        short8 aq = rdA(Hb1, isv?8:12, lane);
        f32x4 c0={0.f,0.f,0.f,0.f}, c1={0.f,0.f,0.f,0.f};
        c0=mm(a0,yA0,c0); c0=mm(a1,yA1,c0);
        c1=mm(a0,yB0,c1); c1=mm(a1,yB1,c1);
        stD(Hb0, ntA*16, lane, c0, true);
        stD(Hb0, ntB*16, lane, c1, true);
        f32x4 cq0={0.f,0.f,0.f,0.f}, cq1={0.f,0.f,0.f,0.f};
        cq0=mm(aq,yQ0,cq0); cq1=mm(aq,yQ1,cq1);
        stD(Hb0, (isv?64:96)+0,  lane, cq0, true);
        stD(Hb0, (isv?64:96)+16, lane, cq1, true);
      }
      __syncthreads();
      // ======== phase D: L3 (d,e heads computed in-register; v -> vh3f) ========
      {
        short8 a0 = rdA(Hb0,0,lane), a1 = rdA(Hb0,4,lane);
        short8 aq = rdA(Hb0, isv?8:12, lane);
        f32x4 c0={0.f,0.f,0.f,0.f}, c1={0.f,0.f,0.f,0.f};
        c0=mm(a0,zA0,c0); c0=mm(a1,zA1,c0);
        c1=mm(a0,zB0,c1); c1=mm(a1,zB1,c1);
        // d-head partial: pd[i2] = relu(c0)*wdA + relu(c1)*wdB, reduce over 16 lanes
        f32x4 pd;
        #pragma unroll
        for (int i2=0;i2<4;++i2)
          pd[i2] = fmaf(fmaxf(c0[i2],0.f), wdA, fmaxf(c1[i2],0.f)*wdB);
        f32x4 cq0={0.f,0.f,0.f,0.f}, cq1={0.f,0.f,0.f,0.f};
        cq0=mm(aq,zQ0,cq0); cq1=mm(aq,zQ1,cq1);
        #pragma unroll
        for (int mk=1; mk<16; mk<<=1){
          #pragma unroll
          for (int i2=0;i2<4;++i2) pd[i2] += __shfl_xor(pd[i2], mk);
        }
        if ((lane&15)==0){
          int rg = (lane>>4)<<2;
          #pragma unroll
          for (int i2=0;i2<4;++i2) ydp[wid][rg+i2] = pd[i2];
        }
        if (isv){
          #pragma unroll
          for (int i2=0;i2<4;++i2){
            int r0 = ((lane>>4)<<2) + i2;
            vh3f[r0*40 +      (lane&15)] = fmaxf(cq0[i2], 0.f);
            vh3f[r0*40 + 16 + (lane&15)] = fmaxf(cq1[i2], 0.f);
          }
        } else {
          // e-head partial
          f32x4 pe;
          #pragma unroll
          for (int i2=0;i2<4;++i2)
            pe[i2] = fmaf(fmaxf(cq0[i2],0.f), weA, fmaxf(cq1[i2],0.f)*weB);
          #pragma unroll
          for (int mk=1; mk<16; mk<<=1){
            #pragma unroll
            for (int i2=0;i2<4;++i2) pe[i2] += __shfl_xor(pe[i2], mk);
          }
          if ((lane&15)==0){
            int rg = (lane>>4)<<2;
            #pragma unroll
            for (int i2=0;i2<4;++i2) ype[rg+i2] = pe[i2];
          }
        }
      }
      __syncthreads();
      // ======== phase F: heads (LDS broadcast) + scalars + G-accum ========
      {
        const float y    = ydp[0][r] + ydp[1][r] + dboS;
        const float yep  = ype[r];
        const float diff = softplusf(y);
        const float zv   = zper[r*30 + (ii-1)];
        const float dWn  = SQH * zv;
        const float d1 = 1.f + (RRATE*SQH)*S;
        const float d2 = 1.f + S*diff*SQH;
        const float Snew = S + (RRATE*HSTEP)*S*__builtin_amdgcn_rcpf(d1)
                             + S*diff*dWn*__builtin_amdgcn_rcpf(d2);
        const float disc = dtab[ii-1];
        const float coef = disc * S * diff * dWn;
        cvE = fmaf(coef, yep + eboS, cvE);
        runmax = fmaxf(runmax, Snew);
        {
          f32x4 vv = *(const f32x4*)&vh3f[r*40 + cc*4];  // col 30 == 1.0 -> G[30] = C
          #pragma unroll
          for (int k=0;k<4;++k) G_[k] = fmaf(coef, vv[k], G_[k]);
        }
        S = Snew;

        if (ii==PER){
          short4v gv;
          #pragma unroll
          for (int k=0;k<4;++k){ gv[k] = (short)f2bf(G_[k]); G_[k] = 0.f; }
          *(short4v*)((char*)Hb0 + swaddr(r, cc>>1, (cc&1)*8)) = gv;
          if (cc==0) Sb[r] = S;
        }
      }

      if (ii==PER){
        __syncthreads();
        // ======== M2: RR += [G|C] @ [vWo;vbo] ; pr stats (6 col-tiles / 2 waves) ========
        const float disc_i = __expf(-RRATE * ((float)(p+1) * 0.25f));
        const float* vWop = vWo + p*2520;
        const float* vbop = vbo + p*84;
        #pragma unroll
        for (int q3=0;q3<3;++q3){
          const int ntr = wid*3 + q3;         // 0..5
          short8 a = rdA(Hb0, 0, lane);
          const int col = ntr*16 + (lane&15);
          short8 bw;
          #pragma unroll
          for (int i2=0;i2<8;++i2){
            int k = ((lane>>4)<<3)+i2;
            float w = 0.f;
            if (col < 84){
              if (k < 30)       w = vWop[k*84+col];
              else if (k == 30) w = vbop[col];
            }
            bw[i2] = (short)f2bf(w);
          }
          f32x4 d4 = {0.f,0.f,0.f,0.f};
          d4 = mm(a,bw,d4);
          const int s = col - p*NSTR;
          const bool inr = (s>=0) && (s<NSTR) && (col<84);
          const float K = strikef(s);
          float ssum=0.f, ssq=0.f;
          #pragma unroll
          for (int i2=0;i2<4;++i2){
            int row = ((lane>>4)<<2) + i2;
            rr[q3][i2] += d4[i2];
            if (inr){
              float pr = disc_i*fmaxf(Sb[row]-K,0.f) - rr[q3][i2];
              ssum += pr; ssq = fmaf(pr,pr,ssq);
            }
          }
          ssum += __shfl_down(ssum,16); ssum += __shfl_down(ssum,32);
          ssq  += __shfl_down(ssq ,16); ssq  += __shfl_down(ssq ,32);
          if (inr && lane<16){
            part[col*2+0] = ssum;
            part[col*2+1] = ssq;
          }
        }
        __syncthreads();
        // ======== M3: write per-block partials ========
        if (tid < NSTR){
          int cidx = p*NSTR + tid;
          ws[WS_PRPART + (cidx*2+0)*NBLK + blk] = part[cidx*2];
        } else if (tid >= 64 && tid < 64+NSTR){
          int cidx = p*NSTR + (tid-64);
          ws[WS_PRPART + (cidx*2+1)*NBLK + blk] = part[cidx*2+1];
        }
        __syncthreads();   // protect LDS from next period's staging writes
      }
    }
  }

  // ---- epilogue ----
  if (cc==0){
    const float discT = __expf(-RRATE);
    const float e = discT * (runmax - S);
    out[OUT_PEXO + blk*NSAMP + r] = e - cvE;
    ebuf[r] = e;
  }
  __syncthreads();
  if (tid < 16){
    float se = ebuf[tid];
    se += __shfl_down(se,8); se += __shfl_down(se,4);
    se += __shfl_down(se,2); se += __shfl_down(se,1);
    if (tid==0) ws[WS_EPART + blk] = se;
  }
}

extern "C" __global__ void fin_pv(const float* __restrict__ ws, float* __restrict__ out){
  const int t = threadIdx.x;
  if (t >= NMAT*NSTR) return;
  float sum=0.0f, ssq=0.0f;
  for (int b=0;b<NBLK;++b){
    sum += ws[WS_PRPART + (t*2+0)*NBLK + b];
    ssq += ws[WS_PRPART + (t*2+1)*NBLK + b];
  }
  out[OUT_PV  + t] = sum * (1.0f/MC);
  out[OUT_PVV + t] = (ssq - sum*sum*(1.0f/MC)) * (1.0f/(MC-1));
}

extern "C" __global__ void fin_pe(float* out, float* ws){
  __shared__ float sA[4], sB[4], sC[4];
  const int t = threadIdx.x;
  float sum=0.0f, ssq=0.0f;
  for (int idx=t; idx<MC; idx+=256){
    const float v = out[OUT_PEXO+idx];
    sum += v; ssq = fmaf(v,v,ssq);
  }
  float es = 0.0f;
  for (int idx=t; idx<NBLK; idx+=256) es += ws[WS_EPART + idx];
  for (int o=32;o>0;o>>=1){
    sum += __shfl_down(sum,o);
    ssq += __shfl_down(ssq,o);
    es  += __shfl_down(es,o);
  }
  const int w=t>>6, lane=t&63;
  if (lane==0){ sA[w]=sum; sB[w]=ssq; sC[w]=es; }
  __syncthreads();
  if (t==0){
    const float s=sA[0]+sA[1]+sA[2]+sA[3];
    const float q=sB[0]+sB[1]+sB[2]+sB[3];
    const float e=sC[0]+sC[1]+sC[2]+sC[3];
    out[OUT_MEAN]=s*(1.0f/MC);
    out[OUT_VAR]=(q - s*s*(1.0f/MC))*(1.0f/(MC-1));
    ws[WS_MEANE]=e*(1.0f/MC);
  }
}

extern "C" __global__ void fin_err(float* out, const float* __restrict__ ws){
  const int m = blockIdx.x*blockDim.x + threadIdx.x;
  if (m < MC) out[OUT_ERR+m] = out[OUT_PEXO+m] - ws[WS_MEANE];
}

extern "C" void kernel_launch(void* const* d_in, const int* in_sizes, int n_in,
                              void* d_out, int out_size, void* d_ws, size_t ws_size,
                              hipStream_t stream){
  (void)in_sizes; (void)n_in; (void)out_size; (void)ws_size;
  const float* S0 =(const float*)d_in[0];
  const float* z  =(const float*)d_in[1];
  const float* dW0=(const float*)d_in[2];
  const float* db0=(const float*)d_in[3];
  const float* dhW=(const float*)d_in[4];
  const float* dhb=(const float*)d_in[5];
  const float* dWo=(const float*)d_in[6];
  const float* dbo=(const float*)d_in[7];
  const float* vW0=(const float*)d_in[8];
  const float* vb0=(const float*)d_in[9];
  const float* vhW=(const float*)d_in[10];
  const float* vhb=(const float*)d_in[11];
  const float* vWo=(const float*)d_in[12];
  const float* vbo=(const float*)d_in[13];
  const float* eW0=(const float*)d_in[14];
  const float* eb0=(const float*)d_in[15];
  const float* ehW=(const float*)d_in[16];
  const float* ehb=(const float*)d_in[17];
  const float* eWo=(const float*)d_in[18];
  const float* ebo=(const float*)d_in[19];
  float* out=(float*)d_out;
  float* ws =(float*)d_ws;

  mk_frags<<<dim3(NMAT*36),dim3(64),0,stream>>>(dhW,dhb,vhW,vhb,ehW,ehb,ws);
  mc_main<<<dim3(NBLK),dim3(128),0,stream>>>(S0,z,dW0,db0,dhW,dhb,dWo,dbo,
                                             vW0,vb0,vhW,vhb,vWo,vbo,
                                             eW0,eb0,ehW,ehb,eWo,ebo,out,ws);
  fin_pv <<<dim3(1), dim3(128),0,stream>>>(ws,out);
  fin_pe <<<dim3(1), dim3(256),0,stream>>>(out,ws);
  fin_err<<<dim3(64),dim3(256),0,stream>>>(out,ws);
}